// Round 4
// baseline (139.379 us; speedup 1.0000x reference)
//
#include <hip/hip_runtime.h>

// Bilinear backward warp: img [B,C,H,W] f32, flo [B,2,H,W] f32 -> out [B,C,H,W] f32
// B=8, C=64, H=256, W=448
//
// R4: 3-buffer LDS pipeline with counted vmcnt(3) + raw s_barrier (one barrier
// per channel, prefetch stays in flight across it), 16B-granular XOR bank
// swizzle applied via pre-swizzled global source (LDS dest stays linear for
// global_load_lds), wave-uniform fallback hoisting.

#define BN 8
#define CN 64
#define HN 256
#define WN 448
#define HW (HN * WN)
#define R 4              // output rows per block
#define BAND 12          // staged img rows per channel (lo = h0-4)
#define NBUF 3
#define TPB WN           // 448 threads = 7 waves
#define NXCD 8

typedef __attribute__((address_space(1))) const void glb_v;
typedef __attribute__((address_space(3))) void lds_v;

// swizzled word index within the band: 4-word blocks XORed by row&7
__device__ __forceinline__ int swz(int row, int x) {
    return row * WN + ((((x >> 2) ^ (row & 7)) << 2) | (x & 3));
}

__global__ __launch_bounds__(TPB) void warp_kernel(const float* __restrict__ img,
                                                   const float* __restrict__ flo,
                                                   float* __restrict__ out) {
    __shared__ float lds[NBUF][BAND * WN];   // 3 * 5376 * 4 = 64512 B -> 2 blocks/CU

    // XCD swizzle: grid = 512 = 8 x 64; XCD k owns batch k.
    const int nwg = gridDim.x;          // 512
    const int cpx = nwg / NXCD;         // 64
    const int bid = blockIdx.x;
    const int wgid = (bid % NXCD) * cpx + (bid / NXCD);

    const int b    = wgid / (HN / R);   // 0..7
    const int tile = wgid % (HN / R);   // 0..63
    const int h0   = tile * R;
    const int w    = threadIdx.x;       // 0..447

    int lo = h0 - 4;
    lo = lo < 0 ? 0 : (lo > HN - BAND ? HN - BAND : lo);

    const float* imgb = img + (size_t)b * CN * HW;
    const float* flob = flo + (size_t)b * 2 * HW;

    // ---- per-pixel setup, channel-invariant ----
    float wa[R], wb[R], wc[R], wd[R];
    int sA0[R], sA1[R], sB0[R], sB1[R];     // swizzled LDS word offsets
    int gA0[R], gA1[R], gB0[R], gB1[R];     // plane-relative global words (fallback)
    bool fb[R];
    bool anyfb = false;
#pragma unroll
    for (int r = 0; r < R; ++r) {
        const int h = h0 + r;
        const int hw = h * WN + w;
        const float fx = flob[hw];
        const float fy = flob[HW + hw];
        const float x = (float)w + fx;
        const float y = (float)h + fy;
        int x0 = (int)x;                 // trunc toward zero (matches ref)
        int x1 = x0 + 1;
        int y0 = (int)y;
        int y1 = y0 + 1;
        x0 = min(max(x0, 0), WN - 1);
        x1 = min(max(x1, 0), WN - 1);
        y0 = min(max(y0, 0), HN - 1);
        y1 = min(max(y1, 0), HN - 1);
        const float x0f = (float)x0, x1f = (float)x1;
        const float y0f = (float)y0, y1f = (float)y1;
        wa[r] = (x1f - x) * (y1f - y);
        wb[r] = (x1f - x) * (y - y0f);
        wc[r] = (x - x0f) * (y1f - y);
        wd[r] = (x - x0f) * (y - y0f);
        const bool inband = (y0 >= lo) && (y1 <= lo + BAND - 1);
        fb[r] = !inband;
        anyfb |= fb[r];
        const int rA = min(max(y0 - lo, 0), BAND - 1);   // clamped so LDS idx valid
        const int rB = min(max(y1 - lo, 0), BAND - 1);
        sA0[r] = swz(rA, x0); sA1[r] = swz(rA, x1);
        sB0[r] = swz(rB, x0); sB1[r] = swz(rB, x1);
        gA0[r] = y0 * WN + x0; gA1[r] = y0 * WN + x1;
        gB0[r] = y1 * WN + x0; gB1[r] = y1 * WN + x1;
    }
    const bool dirty = __any(anyfb);    // wave-uniform (P ~ 1e-5 per lane)

    // ---- staging offsets: 21 chunks x 1KB, 3 per wave, uniform ----
    const int wv = threadIdx.x >> 6;    // 0..6
    const int lane = threadIdx.x & 63;
    int srcW[3];                        // pre-swizzled global word (band-relative)
    int dstB[3];                        // linear LDS byte offset
#pragma unroll
    for (int s = 0; s < 3; ++s) {
        const int k = wv * 3 + s;           // 0..20
        const int W = k * 256 + lane * 4;   // linear LDS word
        const int r = W / WN;
        const int blk = (W - r * WN) >> 2;
        srcW[s] = r * WN + ((blk ^ (r & 7)) << 2);
        dstB[s] = W * 4;
    }

    auto stage = [&](int bufi, int c) {
        const float* src = imgb + (size_t)c * HW + (size_t)lo * WN;
        char* dst = (char*)&lds[bufi][0];
#pragma unroll
        for (int s = 0; s < 3; ++s) {
            __builtin_amdgcn_global_load_lds((glb_v*)(src + srcW[s]),
                                             (lds_v*)(dst + dstB[s]), 16, 0, 0);
        }
    };

    stage(0, 0);
    stage(1, 1);

    float* outp = out + (size_t)b * CN * HW + (size_t)h0 * WN + w;

    for (int c = 0; c < CN; ++c) {
        // counted wait: stage c's 3 loads are the oldest outstanding VMEM;
        // <=3 outstanding guarantees they landed (stage c+1 may stay in flight).
        if (c < CN - 1) {
            asm volatile("s_waitcnt vmcnt(3)" ::: "memory");
        } else {
            asm volatile("s_waitcnt vmcnt(0)" ::: "memory");
        }
        __builtin_amdgcn_s_barrier();   // raw barrier: no vmcnt(0) drain
        if (c + 2 < CN) stage((c + 2) % NBUF, c + 2);  // after barrier: buf free

        const float* buf = &lds[c % NBUF][0];
        float o[R];
        if (!dirty) {
#pragma unroll
            for (int r = 0; r < R; ++r) {
                const float Ia = buf[sA0[r]];
                const float Ic = buf[sA1[r]];
                const float Ib = buf[sB0[r]];
                const float Id = buf[sB1[r]];
                o[r] = wa[r] * Ia + wb[r] * Ib + wc[r] * Ic + wd[r] * Id;
            }
        } else {
            const float* pg = imgb + (size_t)c * HW;
#pragma unroll
            for (int r = 0; r < R; ++r) {
                float Ia = buf[sA0[r]];
                float Ic = buf[sA1[r]];
                float Ib = buf[sB0[r]];
                float Id = buf[sB1[r]];
                if (fb[r]) {
                    Ia = pg[gA0[r]];
                    Ic = pg[gA1[r]];
                    Ib = pg[gB0[r]];
                    Id = pg[gB1[r]];
                }
                o[r] = wa[r] * Ia + wb[r] * Ib + wc[r] * Ic + wd[r] * Id;
            }
        }
#pragma unroll
        for (int r = 0; r < R; ++r) {
            outp[(size_t)c * HW + r * WN] = o[r];
        }
    }
}

extern "C" void kernel_launch(void* const* d_in, const int* in_sizes, int n_in,
                              void* d_out, int out_size, void* d_ws, size_t ws_size,
                              hipStream_t stream) {
    const float* img = (const float*)d_in[0];
    const float* flo = (const float*)d_in[1];
    float* out = (float*)d_out;

    const int grid = BN * (HN / R);   // 512 blocks
    warp_kernel<<<grid, TPB, 0, stream>>>(img, flo, out);
}